// Round 1
// baseline (191.394 us; speedup 1.0000x reference)
//
#include <hip/hip_runtime.h>

// YOLO v1-style loss, forward only.
// prediction: [32768, 7, 7, 12] f32   (B=2 boxes * 5 + C=2 classes)
// target:     [32768, 7, 7, 7]  f32   (x,y,w,h,obj, c0,c1)
// output:     scalar f32

constexpr int S = 7;
constexpr int CELLS = 32768 * S * S;          // 1,605,632
constexpr float LAMBDA_COORD = 5.0f;
constexpr float LAMBDA_NOOBJ = 0.5f;
constexpr float INV_S = 1.0f / 7.0f;

__device__ inline float iou_vs_target(float bx, float by, float bw, float bh,
                                      float fcol, float frow,
                                      float tx1, float ty1, float tx2, float ty2,
                                      float ta) {
    // corners of pred box (matches reference _to_corners)
    float cx = (bx + fcol) * INV_S;
    float cy = (by + frow) * INV_S;
    float x1 = cx - bw * 0.5f, y1 = cy - bh * 0.5f;
    float x2 = cx + bw * 0.5f, y2 = cy + bh * 0.5f;
    float ix1 = fmaxf(x1, tx1), iy1 = fmaxf(y1, ty1);
    float ix2 = fminf(x2, tx2), iy2 = fminf(y2, ty2);
    float inter = fmaxf(ix2 - ix1, 0.0f) * fmaxf(iy2 - iy1, 0.0f);
    float a1 = fabsf((x2 - x1) * (y2 - y1));
    return inter / (a1 + ta - inter + 1e-8f);
}

__global__ __launch_bounds__(256)
void yolo_loss_kernel(const float* __restrict__ pred,
                      const float* __restrict__ targ,
                      double* __restrict__ ws) {
    int idx = blockIdx.x * blockDim.x + threadIdx.x;
    float cell_loss = 0.0f;

    if (idx < CELLS) {
        int j = idx % S;              // col (third axis)
        int i = (idx / S) % S;        // row (second axis)
        float fcol = (float)j;
        float frow = (float)i;

        const float* p = pred + (size_t)idx * 12;   // 48B stride, 16B aligned
        const float* t = targ + (size_t)idx * 7;    // 28B stride

        float4 pa = *reinterpret_cast<const float4*>(p);       // x0 y0 w0 h0
        float4 pb = *reinterpret_cast<const float4*>(p + 4);   // p0 x1 y1 w1
        float4 pc = *reinterpret_cast<const float4*>(p + 8);   // h1 p1 c0 c1

        float x0 = pa.x, y0 = pa.y, w0 = pa.z, h0 = pa.w, conf0 = pb.x;
        float x1 = pb.y, y1 = pb.z, w1 = pb.w, h1 = pc.x, conf1 = pc.y;
        float pcls0 = pc.z, pcls1 = pc.w;

        float tx = t[0], ty = t[1], tw = t[2], th = t[3], tp = t[4];
        float tc0 = t[5], tc1 = t[6];

        // target corners
        float tcx = (tx + fcol) * INV_S;
        float tcy = (ty + frow) * INV_S;
        float tx1c = tcx - tw * 0.5f, ty1c = tcy - th * 0.5f;
        float tx2c = tcx + tw * 0.5f, ty2c = tcy + th * 0.5f;
        float ta = fabsf((tx2c - tx1c) * (ty2c - ty1c));

        float iou0 = iou_vs_target(x0, y0, w0, h0, fcol, frow, tx1c, ty1c, tx2c, ty2c, ta);
        float iou1 = iou_vs_target(x1, y1, w1, h1, fcol, frow, tx1c, ty1c, tx2c, ty2c, ta);

        // argmax: box 1 only if strictly greater (jnp.argmax picks first max)
        bool sel1 = iou1 > iou0;
        float px = sel1 ? x1 : x0;
        float py = sel1 ? y1 : y0;
        float pw = sel1 ? w1 : w0;
        float ph = sel1 ? h1 : h0;
        float pp = sel1 ? conf1 : conf0;

        float obj = (tp > 0.0f) ? 1.0f : 0.0f;
        float noobj = 1.0f - obj;

        float dx = px - tx, dy = py - ty;
        float centre = dx * dx + dy * dy;

        float sgnw = (pw > 0.0f) ? 1.0f : ((pw < 0.0f) ? -1.0f : 0.0f);
        float sgnh = (ph > 0.0f) ? 1.0f : ((ph < 0.0f) ? -1.0f : 0.0f);
        float dw = sgnw * sqrtf(fabsf(pw) + 1e-6f) - sqrtf(tw);
        float dh = sgnh * sqrtf(fabsf(ph) + 1e-6f) - sqrtf(th);
        float dim = dw * dw + dh * dh;

        float dconf = pp - tp;
        float conf = dconf * dconf;

        float n0 = conf0 - tp, n1 = conf1 - tp;
        float noconf = n0 * n0 + n1 * n1;

        float dc0 = pcls0 - tc0, dc1 = pcls1 - tc1;
        float cls = dc0 * dc0 + dc1 * dc1;

        cell_loss = obj * (LAMBDA_COORD * (centre + dim) + conf + cls)
                  + noobj * LAMBDA_NOOBJ * noconf;
    }

    // block reduction in double: wave64 shuffle -> LDS -> one atomic per block
    double v = (double)cell_loss;
    #pragma unroll
    for (int off = 32; off > 0; off >>= 1)
        v += __shfl_down(v, off, 64);

    __shared__ double sm[4];
    int lane = threadIdx.x & 63;
    int wid  = threadIdx.x >> 6;
    if (lane == 0) sm[wid] = v;
    __syncthreads();
    if (threadIdx.x == 0) {
        double s = sm[0] + sm[1] + sm[2] + sm[3];
        atomicAdd(ws, s);
    }
}

__global__ void finalize_kernel(const double* __restrict__ ws, float* __restrict__ out) {
    out[0] = (float)ws[0];
}

extern "C" void kernel_launch(void* const* d_in, const int* in_sizes, int n_in,
                              void* d_out, int out_size, void* d_ws, size_t ws_size,
                              hipStream_t stream) {
    const float* pred = (const float*)d_in[0];
    const float* targ = (const float*)d_in[1];
    float* out = (float*)d_out;
    double* ws = (double*)d_ws;

    hipMemsetAsync(ws, 0, sizeof(double), stream);

    int blocks = (CELLS + 255) / 256;   // 6272
    yolo_loss_kernel<<<blocks, 256, 0, stream>>>(pred, targ, ws);
    finalize_kernel<<<1, 1, 0, stream>>>(ws, out);
}

// Round 2
// 163.665 us; speedup vs baseline: 1.1694x; 1.1694x over previous
//
#include <hip/hip_runtime.h>

// YOLO v1-style loss, forward only.
// prediction: [32768, 7, 7, 12] f32   (B=2 boxes * 5 + C=2 classes)
// target:     [32768, 7, 7, 7]  f32   (x,y,w,h,obj, c0,c1)
// output:     scalar f32
//
// 4 cells per thread: pred 4*12=48 floats = 12 float4 (16B aligned),
// targ 4*7=28 floats = 7 float4 (16B aligned since 112 = 7*16).
// All 19 loads issued up-front -> deep MLP/ILP, latency-bound fix.

constexpr int S = 7;
constexpr int CELLS = 32768 * S * S;          // 1,605,632
constexpr int CPT = 4;                        // cells per thread
constexpr int NTHREADS = CELLS / CPT;         // 401,408
constexpr float LAMBDA_COORD = 5.0f;
constexpr float LAMBDA_NOOBJ = 0.5f;
constexpr float INV_S = 1.0f / 7.0f;

// one cell's loss; p -> 12 floats, t -> 7 floats (constant-indexed after unroll)
__device__ __forceinline__ float cell_loss(const float* p, const float* t,
                                           float fcol, float frow) {
    float x0 = p[0], y0 = p[1], w0 = p[2], h0 = p[3], c0 = p[4];
    float x1 = p[5], y1 = p[6], w1 = p[7], h1 = p[8], c1 = p[9];
    float q0 = p[10], q1 = p[11];
    float tx = t[0], ty = t[1], tw = t[2], th = t[3], tp = t[4];
    float s0 = t[5], s1 = t[6];

    // target corners + area
    float tcx = (tx + fcol) * INV_S, tcy = (ty + frow) * INV_S;
    float tX1 = tcx - tw * 0.5f, tY1 = tcy - th * 0.5f;
    float tX2 = tcx + tw * 0.5f, tY2 = tcy + th * 0.5f;
    float ta = fabsf((tX2 - tX1) * (tY2 - tY1));

    // box 0 corners
    float cx0 = (x0 + fcol) * INV_S, cy0 = (y0 + frow) * INV_S;
    float aX1 = cx0 - w0 * 0.5f, aY1 = cy0 - h0 * 0.5f;
    float aX2 = cx0 + w0 * 0.5f, aY2 = cy0 + h0 * 0.5f;
    float inter0 = fmaxf(fminf(aX2, tX2) - fmaxf(aX1, tX1), 0.0f) *
                   fmaxf(fminf(aY2, tY2) - fmaxf(aY1, tY1), 0.0f);
    float ar0 = fabsf((aX2 - aX1) * (aY2 - aY1));
    float u0 = ar0 + ta - inter0 + 1e-8f;      // > 0 always

    // box 1 corners
    float cx1 = (x1 + fcol) * INV_S, cy1 = (y1 + frow) * INV_S;
    float bX1 = cx1 - w1 * 0.5f, bY1 = cy1 - h1 * 0.5f;
    float bX2 = cx1 + w1 * 0.5f, bY2 = cy1 + h1 * 0.5f;
    float inter1 = fmaxf(fminf(bX2, tX2) - fmaxf(bX1, tX1), 0.0f) *
                   fmaxf(fminf(bY2, tY2) - fmaxf(bY1, tY1), 0.0f);
    float ar1 = fabsf((bX2 - bX1) * (bY2 - bY1));
    float u1 = ar1 + ta - inter1 + 1e-8f;

    // argmax(iou): box1 iff iou1 > iou0  <=>  inter1*u0 > inter0*u1 (u>0)
    bool sel1 = inter1 * u0 > inter0 * u1;
    float px = sel1 ? x1 : x0;
    float py = sel1 ? y1 : y0;
    float pw = sel1 ? w1 : w0;
    float ph = sel1 ? h1 : h0;
    float pp = sel1 ? c1 : c0;

    float obj = (tp > 0.0f) ? 1.0f : 0.0f;
    float noobj = 1.0f - obj;

    float dx = px - tx, dy = py - ty;
    float centre = dx * dx + dy * dy;

    float sgnw = (pw > 0.0f) ? 1.0f : ((pw < 0.0f) ? -1.0f : 0.0f);
    float sgnh = (ph > 0.0f) ? 1.0f : ((ph < 0.0f) ? -1.0f : 0.0f);
    float dw = sgnw * sqrtf(fabsf(pw) + 1e-6f) - sqrtf(tw);
    float dh = sgnh * sqrtf(fabsf(ph) + 1e-6f) - sqrtf(th);
    float dim = dw * dw + dh * dh;

    float dconf = pp - tp;
    float n0 = c0 - tp, n1 = c1 - tp;
    float dc0 = q0 - s0, dc1 = q1 - s1;

    return obj * (LAMBDA_COORD * (centre + dim) + dconf * dconf + dc0 * dc0 + dc1 * dc1)
         + noobj * LAMBDA_NOOBJ * (n0 * n0 + n1 * n1);
}

__global__ __launch_bounds__(256)
void yolo_loss_kernel(const float* __restrict__ pred,
                      const float* __restrict__ targ,
                      double* __restrict__ ws) {
    int tid = blockIdx.x * blockDim.x + threadIdx.x;
    int base = tid * CPT;

    // issue all 19 float4 loads up-front
    float4 pv[12];
    float4 tv[7];
    const float4* p4 = reinterpret_cast<const float4*>(pred + (size_t)base * 12);
    const float4* t4 = reinterpret_cast<const float4*>(targ + (size_t)base * 7);
    #pragma unroll
    for (int k = 0; k < 12; ++k) pv[k] = p4[k];
    #pragma unroll
    for (int k = 0; k < 7; ++k) tv[k] = t4[k];

    const float* pf = reinterpret_cast<const float*>(pv);
    const float* tf = reinterpret_cast<const float*>(tv);

    // cell coords for the 4 consecutive cells (avoid 8 div/mods)
    int j = base % S;
    int i = (base / S) % S;

    float acc = 0.0f;
    #pragma unroll
    for (int k = 0; k < CPT; ++k) {
        acc += cell_loss(pf + k * 12, tf + k * 7, (float)j, (float)i);
        if (++j == S) { j = 0; if (++i == S) i = 0; }
    }

    // block reduction in double: wave64 shuffle -> LDS -> one atomic per block
    double v = (double)acc;
    #pragma unroll
    for (int off = 32; off > 0; off >>= 1)
        v += __shfl_down(v, off, 64);

    __shared__ double sm[4];
    int lane = threadIdx.x & 63;
    int wid  = threadIdx.x >> 6;
    if (lane == 0) sm[wid] = v;
    __syncthreads();
    if (threadIdx.x == 0) {
        double s = sm[0] + sm[1] + sm[2] + sm[3];
        atomicAdd(ws, s);
    }
}

__global__ void finalize_kernel(const double* __restrict__ ws, float* __restrict__ out) {
    out[0] = (float)ws[0];
}

extern "C" void kernel_launch(void* const* d_in, const int* in_sizes, int n_in,
                              void* d_out, int out_size, void* d_ws, size_t ws_size,
                              hipStream_t stream) {
    const float* pred = (const float*)d_in[0];
    const float* targ = (const float*)d_in[1];
    float* out = (float*)d_out;
    double* ws = (double*)d_ws;

    hipMemsetAsync(ws, 0, sizeof(double), stream);

    yolo_loss_kernel<<<NTHREADS / 256, 256, 0, stream>>>(pred, targ, ws);
    finalize_kernel<<<1, 1, 0, stream>>>(ws, out);
}